// Round 1
// baseline (439.214 us; speedup 1.0000x reference)
//
#include <hip/hip_runtime.h>
#include <hip/hip_bf16.h>
#include <math.h>

// ---- problem constants ----
#define NN 32768
#define D 512
#define NL 8
#define BM 128          // GEMM M tile (level segments padded to this)
#define PADMAX 33792    // max padded rows: <=264 tiles of 128
#define MT_MAX 264

typedef __attribute__((ext_vector_type(8))) short short8;
typedef __attribute__((ext_vector_type(8))) __bf16 bf16x8;
typedef __attribute__((ext_vector_type(4))) float f32x4;
typedef __attribute__((ext_vector_type(4))) unsigned short us4;

__device__ __forceinline__ unsigned short f2bf(float f){
  unsigned u = __builtin_bit_cast(unsigned, f);
  u += 0x7FFFu + ((u>>16)&1u);           // RNE
  return (unsigned short)(u>>16);
}
__device__ __forceinline__ float bf2f(unsigned short s){
  return __builtin_bit_cast(float, ((unsigned)s)<<16);
}
__device__ __forceinline__ float tanh_fast(float x){
  float e = __expf(2.f*x);               // v_exp-based; inf/0 saturate correctly
  return 1.f - 2.f*__builtin_amdgcn_rcpf(1.f+e);
}

// ---- ws bookkeeping kernels ----
__global__ void k_zero(float* w0){
  int t = blockIdx.x*blockDim.x + threadIdx.x;
  for(int i=t;i<4160;i+=gridDim.x*blockDim.x) w0[i]=0.f;  // counts/cursors/poff/sums
}

__global__ void k_hist(const int* __restrict__ lv, int* __restrict__ counts){
  __shared__ int h[NL];
  if(threadIdx.x<NL) h[threadIdx.x]=0;
  __syncthreads();
  for(int i=blockIdx.x*blockDim.x+threadIdx.x; i<NN; i+=gridDim.x*blockDim.x)
    atomicAdd(&h[lv[i]],1);
  __syncthreads();
  if(threadIdx.x<NL) atomicAdd(&counts[threadIdx.x], h[threadIdx.x]);
}

__global__ void k_offsets(const int* __restrict__ counts, int* __restrict__ poff, int* __restrict__ cursors){
  if(threadIdx.x==0 && blockIdx.x==0){
    int acc=0;
    for(int l=0;l<NL;l++){ poff[l]=acc; cursors[l]=acc; acc += (counts[l]+BM-1)/BM*BM; }
    poff[NL]=acc;
  }
}

__global__ void k_scatter(const int* __restrict__ lv, int* __restrict__ cursors, int* __restrict__ perm){
  int i = blockIdx.x*blockDim.x+threadIdx.x;
  if(i<NN){ int pos = atomicAdd(&cursors[lv[i]],1); perm[pos]=i; }
}

// ---- transpose+convert weights: Wt[n][k] bf16 (so MFMA B-frag reads are contiguous) ----
__global__ __launch_bounds__(256) void k_trans(const float* __restrict__ Wp, const float* __restrict__ W1a,
                                               unsigned short* __restrict__ WtP, unsigned short* __restrict__ Wt1a){
  int m = blockIdx.z;
  const float* src = (m<NL)? Wp + (size_t)m*D*D : W1a;
  unsigned short* dst = (m<NL)? WtP + (size_t)m*D*D : Wt1a;
  __shared__ unsigned short t[64][68];
  int k0=blockIdx.x*64, n0=blockIdx.y*64;
  int c = threadIdx.x&63, r4 = threadIdx.x>>6;
  for(int p=0;p<64;p+=4){ int r=p+r4; t[r][c] = f2bf(src[(size_t)(k0+r)*D + n0+c]); }
  __syncthreads();
  for(int p=0;p<64;p+=4){ int r=p+r4; dst[(size_t)(n0+r)*D + k0+c] = t[c][r]; }
}

// ---- gather node rows into level-sorted padded order, fp32 -> bf16 ----
__global__ __launch_bounds__(128) void k_gather(const float* __restrict__ X, const int* __restrict__ perm,
                                                const int* __restrict__ poff, const int* __restrict__ counts,
                                                unsigned short* __restrict__ Xg){
  int r = blockIdx.x, t = threadIdx.x;
  int total = poff[NL];
  int idx = -1;
  if(r<total){
    int lvl=0; while(r>=poff[lvl+1]) lvl++;
    if(r - poff[lvl] < counts[lvl]) idx = perm[r];
  }
  us4 pv = (us4){0,0,0,0};
  if(idx>=0){
    f32x4 x = *(const f32x4*)(X + (size_t)idx*D + t*4);
    #pragma unroll
    for(int e=0;e<4;e++) pv[e] = f2bf(x[e]);
  }
  *(us4*)(Xg + (size_t)r*D + t*4) = pv;
}

// ---- bf16 MFMA GEMM: Out[row][n] = Xs[row][:] @ WbT[n][:]  (Wt is pre-transposed) ----
// PROJ: per-level weights + bias + fp32 level-sum accumulation for means.
template<bool PROJ>
__global__ __launch_bounds__(256) void k_gemm(
    const unsigned short* __restrict__ Xs,
    const unsigned short* __restrict__ Wt,
    const float* __restrict__ bias,
    unsigned short* __restrict__ Out,
    float* __restrict__ sums,
    const int* __restrict__ poff,
    const int* __restrict__ counts)
{
  __shared__ unsigned short Asb[BM*64];   // 16KB, 16B-granule XOR swizzled
  __shared__ unsigned short Bsb[64*64];   // 8KB
  __shared__ float lsum[64];
  int row0 = blockIdx.x*BM;
  int total = poff[NL];
  if(row0 >= total) return;
  int n0 = blockIdx.y*64;
  int lvl = 0;
  if(PROJ){ while(row0 >= poff[lvl+1]) lvl++; }
  const unsigned short* Wb = PROJ ? (Wt + (size_t)lvl*D*D) : Wt;
  int tid = threadIdx.x;
  if(PROJ && tid<64) lsum[tid]=0.f;
  int l = tid&63, w=tid>>6;
  int wm = w>>1, wn = w&1;           // 2x2 waves -> 64x32 per wave
  int l15 = l&15, lhi = l>>4;
  f32x4 acc[4][2];
  #pragma unroll
  for(int i=0;i<4;i++)
    #pragma unroll
    for(int j=0;j<2;j++) acc[i][j] = (f32x4){0.f,0.f,0.f,0.f};

  for(int kt=0;kt<D/64;kt++){
    int k0 = kt*64;
    #pragma unroll
    for(int p=0;p<4;p++){             // stage A 128x64
      int flat = p*256+tid;
      int ar = flat>>3, ag = flat&7;
      short8 v = *(const short8*)(Xs + (size_t)(row0+ar)*D + k0 + ag*8);
      *(short8*)(Asb + ar*64 + ((ag^(ar&7))<<3)) = v;
    }
    #pragma unroll
    for(int p=0;p<2;p++){             // stage B^T 64x64
      int flat = p*256+tid;
      int br = flat>>3, bg = flat&7;
      short8 v = *(const short8*)(Wb + (size_t)(n0+br)*D + k0 + bg*8);
      *(short8*)(Bsb + br*64 + ((bg^(br&7))<<3)) = v;
    }
    __syncthreads();
    #pragma unroll
    for(int kk=0;kk<2;kk++){
      int swz = ((kk*4+lhi) ^ (l15&7))<<3;   // (row&7)==(l15&7) for all frag rows
      bf16x8 a[4], b[2];
      #pragma unroll
      for(int fm=0;fm<4;fm++)
        a[fm] = __builtin_bit_cast(bf16x8, *(const short8*)(Asb + (wm*64+fm*16+l15)*64 + swz));
      #pragma unroll
      for(int fn=0;fn<2;fn++)
        b[fn] = __builtin_bit_cast(bf16x8, *(const short8*)(Bsb + (wn*32+fn*16+l15)*64 + swz));
      #pragma unroll
      for(int fm=0;fm<4;fm++)
        #pragma unroll
        for(int fn=0;fn<2;fn++)
          acc[fm][fn] = __builtin_amdgcn_mfma_f32_16x16x32_bf16(a[fm], b[fn], acc[fm][fn], 0,0,0);
    }
    __syncthreads();
  }
  // epilogue: bias, bf16 store, masked column sums (for level means)
  int cnt=0, pb=0;
  if(PROJ){ cnt = counts[lvl]; pb = poff[lvl]; }
  float csum[2] = {0.f,0.f};
  #pragma unroll
  for(int fn=0;fn<2;fn++){
    int col = n0 + wn*32 + fn*16 + l15;
    float bia = PROJ ? bias[lvl*D + col] : 0.f;
    #pragma unroll
    for(int fm=0;fm<4;fm++){
      #pragma unroll
      for(int j=0;j<4;j++){
        int grow = row0 + wm*64 + fm*16 + lhi*4 + j;   // verified C/D mapping
        float v = acc[fm][fn][j] + bia;
        Out[(size_t)grow*D + col] = f2bf(v);
        if(PROJ && (grow-pb)<cnt) csum[fn] += v;
      }
    }
  }
  if(PROJ){
    #pragma unroll
    for(int fn=0;fn<2;fn++){
      float s = csum[fn];
      s += __shfl_xor(s,16);
      s += __shfl_xor(s,32);
      if(lhi==0) atomicAdd(&lsum[wn*32+fn*16+l15], s);
    }
    __syncthreads();
    if(tid<64) atomicAdd(&sums[(size_t)lvl*D + n0 + tid], lsum[tid]);
  }
}

// ---- means -> Bpre = means@W1b + b1 ; MW = means@Wout (both 8x512 fp32) ----
__global__ __launch_bounds__(128) void k_small(
    const float* __restrict__ sums, const int* __restrict__ counts,
    const float* __restrict__ W1b, const float* __restrict__ b1,
    const float* __restrict__ Wout, float* __restrict__ Bpre, float* __restrict__ MW)
{
  int lvl = blockIdx.x, jc = blockIdx.y, t = threadIdx.x;
  __shared__ float mean[D];
  int c = counts[lvl];
  float inv = 1.f / (float)(c>0?c:1);
  for(int k=t;k<D;k+=128) mean[k] = sums[lvl*D+k]*inv;
  __syncthreads();
  int j = jc*128 + t;
  float a=0.f, b=0.f;
  for(int k=0;k<D;k++){ float m = mean[k]; a += m*W1b[(size_t)k*D+j]; b += m*Wout[(size_t)k*D+j]; }
  Bpre[lvl*D+j] = a + b1[j];
  MW[lvl*D+j] = b;
}

// ---- fused: scores(tanh MLP) -> softmax -> o = wts@MW + bout -> LN -> ReLU -> scatter ----
__global__ __launch_bounds__(256) void k_score(
    const unsigned short* __restrict__ Ag, const int* __restrict__ perm,
    const int* __restrict__ poff, const int* __restrict__ counts,
    const float* __restrict__ Bpre, const float* __restrict__ MW,
    const float* __restrict__ w2, const float* __restrict__ b2,
    const float* __restrict__ bout, const float* __restrict__ gamma,
    const float* __restrict__ beta, float* __restrict__ out)
{
  int l = threadIdx.x & 63;
  int r = blockIdx.x*4 + (threadIdx.x>>6);   // one wave per row
  int total = poff[NL];
  if(r >= total) return;
  int lvl=0; while(r>=poff[lvl+1]) lvl++;
  if(r - poff[lvl] >= counts[lvl]) return;   // padding row
  int orig = perm[r];
  short8 av = *(const short8*)(Ag + (size_t)r*D + l*8);
  float a[8], w2v[8];
  #pragma unroll
  for(int e=0;e<8;e++){ a[e] = bf2f((unsigned short)av[e]); w2v[e] = w2[l*8+e]; }
  float sc[NL];
  #pragma unroll
  for(int lev=0;lev<NL;lev++){
    float s = 0.f;
    #pragma unroll
    for(int e=0;e<8;e++) s += w2v[e]*tanh_fast(a[e] + Bpre[lev*D + l*8 + e]);
    #pragma unroll
    for(int off=1; off<64; off<<=1) s += __shfl_xor(s, off);
    sc[lev] = s;
  }
  float b2v = b2[0];
  float mx = -1e30f;
  #pragma unroll
  for(int lev=0;lev<NL;lev++){ sc[lev]+=b2v; if(counts[lev]>0) mx = fmaxf(mx, sc[lev]); }
  float den=0.f, wts[NL];
  #pragma unroll
  for(int lev=0;lev<NL;lev++){ float e = (counts[lev]>0) ? __expf(sc[lev]-mx) : 0.f; wts[lev]=e; den+=e; }
  float iden = 1.f/den;
  #pragma unroll
  for(int lev=0;lev<NL;lev++) wts[lev]*=iden;
  float o[8]; float s1=0.f;
  #pragma unroll
  for(int q=0;q<8;q++){
    int c = l + 64*q;
    float v = bout[c];
    #pragma unroll
    for(int lev=0;lev<NL;lev++) v += wts[lev]*MW[lev*D + c];
    o[q]=v; s1+=v;
  }
  #pragma unroll
  for(int off=1; off<64; off<<=1) s1 += __shfl_xor(s1,off);
  float mu = s1 * (1.f/512.f);
  float s2=0.f;
  #pragma unroll
  for(int q=0;q<8;q++){ float d=o[q]-mu; s2 += d*d; }
  #pragma unroll
  for(int off=1; off<64; off<<=1) s2 += __shfl_xor(s2,off);
  float rs = rsqrtf(s2*(1.f/512.f) + 1e-5f);
  #pragma unroll
  for(int q=0;q<8;q++){
    int c = l + 64*q;
    float y = (o[q]-mu)*rs*gamma[c] + beta[c];
    out[(size_t)orig*D + c] = fmaxf(y, 0.f);
  }
}

extern "C" void kernel_launch(void* const* d_in, const int* in_sizes, int n_in,
                              void* d_out, int out_size, void* d_ws, size_t ws_size,
                              hipStream_t stream) {
  (void)in_sizes; (void)n_in; (void)out_size; (void)ws_size;
  const float* X    = (const float*)d_in[0];
  const int*   lv   = (const int*)  d_in[1];
  const float* Wp   = (const float*)d_in[2];
  const float* bp   = (const float*)d_in[3];
  const float* W1a  = (const float*)d_in[4];
  const float* W1b  = (const float*)d_in[5];
  const float* b1   = (const float*)d_in[6];
  const float* w2   = (const float*)d_in[7];
  const float* b2   = (const float*)d_in[8];
  const float* Wout = (const float*)d_in[9];
  const float* bout = (const float*)d_in[10];
  const float* gmma = (const float*)d_in[11];
  const float* beta = (const float*)d_in[12];
  float* out = (float*)d_out;

  char* ws = (char*)d_ws;
  int*   counts  = (int*)(ws+0);        // 8
  int*   cursors = (int*)(ws+64);       // 8
  int*   poff    = (int*)(ws+128);      // 9
  float* sums    = (float*)(ws+256);    // 8*512
  float* Bpre    = (float*)(ws+16640);  // 8*512
  float* MW      = (float*)(ws+33024);  // 8*512
  int*   perm    = (int*)(ws+49664);    // 33792
  unsigned short* WtP  = (unsigned short*)(ws+186368);          // 8*512*512 bf16
  unsigned short* Wt1a = WtP + (size_t)NL*D*D;                  // 512*512 bf16
  unsigned short* Xg   = (unsigned short*)(ws+4905472);         // 33792*512 bf16
  unsigned short* Hg   = (unsigned short*)(ws+39508480);        // 33792*512 bf16
  unsigned short* Ag   = Xg;   // Xg dead after proj GEMM

  k_zero   <<<dim3(9),   dim3(512), 0, stream>>>((float*)ws);
  k_hist   <<<dim3(64),  dim3(256), 0, stream>>>(lv, counts);
  k_offsets<<<dim3(1),   dim3(64),  0, stream>>>(counts, poff, cursors);
  k_scatter<<<dim3(128), dim3(256), 0, stream>>>(lv, cursors, perm);
  k_trans  <<<dim3(8,8,9), dim3(256), 0, stream>>>(Wp, W1a, WtP, Wt1a);
  k_gather <<<dim3(PADMAX), dim3(128), 0, stream>>>(X, perm, poff, counts, Xg);
  k_gemm<true> <<<dim3(MT_MAX,8), dim3(256), 0, stream>>>(Xg, WtP, bp, Hg, sums, poff, counts);
  k_small  <<<dim3(8,4), dim3(128), 0, stream>>>(sums, counts, W1b, b1, Wout, Bpre, MW);
  k_gemm<false><<<dim3(MT_MAX,8), dim3(256), 0, stream>>>(Hg, Wt1a, nullptr, Ag, sums, poff, counts);
  k_score  <<<dim3(PADMAX/4), dim3(256), 0, stream>>>(Ag, perm, poff, counts, Bpre, MW,
                                                      w2, b2, bout, gmma, beta, out);
}

// Round 2
// 322.985 us; speedup vs baseline: 1.3599x; 1.3599x over previous
//
#include <hip/hip_runtime.h>
#include <hip/hip_bf16.h>
#include <math.h>

// ---- problem constants ----
#define NN 32768
#define D 512
#define NL 8
#define BM 128          // GEMM M tile (level segments padded to this)
#define PADMAX 33792    // max padded rows: <=264 tiles of 128
#define MT_MAX 264

typedef __attribute__((ext_vector_type(8))) short short8;
typedef __attribute__((ext_vector_type(8))) __bf16 bf16x8;
typedef __attribute__((ext_vector_type(4))) float f32x4;
typedef __attribute__((ext_vector_type(4))) unsigned short us4;

__device__ __forceinline__ unsigned short f2bf(float f){
  unsigned u = __builtin_bit_cast(unsigned, f);
  u += 0x7FFFu + ((u>>16)&1u);           // RNE
  return (unsigned short)(u>>16);
}
__device__ __forceinline__ float bf2f(unsigned short s){
  return __builtin_bit_cast(float, ((unsigned)s)<<16);
}
__device__ __forceinline__ float tanh_fast(float x){
  float e = __expf(2.f*x);               // v_exp-based; inf/0 saturate correctly
  return 1.f - 2.f*__builtin_amdgcn_rcpf(1.f+e);
}

// ---- ws bookkeeping kernels ----
__global__ void k_zero(float* w0){
  int t = blockIdx.x*blockDim.x + threadIdx.x;
  for(int i=t;i<4160;i+=gridDim.x*blockDim.x) w0[i]=0.f;  // counts/cursors/poff/sums
}

__global__ void k_hist(const int* __restrict__ lv, int* __restrict__ counts){
  __shared__ int h[NL];
  if(threadIdx.x<NL) h[threadIdx.x]=0;
  __syncthreads();
  for(int i=blockIdx.x*blockDim.x+threadIdx.x; i<NN; i+=gridDim.x*blockDim.x)
    atomicAdd(&h[lv[i]],1);
  __syncthreads();
  if(threadIdx.x<NL) atomicAdd(&counts[threadIdx.x], h[threadIdx.x]);
}

__global__ void k_offsets(const int* __restrict__ counts, int* __restrict__ poff, int* __restrict__ cursors){
  if(threadIdx.x==0 && blockIdx.x==0){
    int acc=0;
    for(int l=0;l<NL;l++){ poff[l]=acc; cursors[l]=acc; acc += (counts[l]+BM-1)/BM*BM; }
    poff[NL]=acc;
  }
}

// contention-free scatter: LDS rank + one global atomic per (block, level)
__global__ __launch_bounds__(256) void k_scatter(const int* __restrict__ lv, int* __restrict__ cursors, int* __restrict__ perm){
  __shared__ int h[NL];
  __shared__ int base[NL];
  int t = threadIdx.x;
  if(t<NL) h[t]=0;
  __syncthreads();
  int i = blockIdx.x*256 + t;
  int lvl = 0, rank = 0;
  if(i<NN){ lvl = lv[i]; rank = atomicAdd(&h[lvl],1); }
  __syncthreads();
  if(t<NL) base[t] = (h[t]>0) ? atomicAdd(&cursors[t], h[t]) : 0;
  __syncthreads();
  if(i<NN) perm[base[lvl] + rank] = i;
}

// ---- transpose+convert weights: Wt[n][k] bf16 (so MFMA B-frag reads are contiguous) ----
__global__ __launch_bounds__(256) void k_trans(const float* __restrict__ Wp, const float* __restrict__ W1a,
                                               unsigned short* __restrict__ WtP, unsigned short* __restrict__ Wt1a){
  int m = blockIdx.z;
  const float* src = (m<NL)? Wp + (size_t)m*D*D : W1a;
  unsigned short* dst = (m<NL)? WtP + (size_t)m*D*D : Wt1a;
  __shared__ unsigned short t[64][68];
  int k0=blockIdx.x*64, n0=blockIdx.y*64;
  int c = threadIdx.x&63, r4 = threadIdx.x>>6;
  for(int p=0;p<64;p+=4){ int r=p+r4; t[r][c] = f2bf(src[(size_t)(k0+r)*D + n0+c]); }
  __syncthreads();
  for(int p=0;p<64;p+=4){ int r=p+r4; dst[(size_t)(n0+r)*D + k0+c] = t[c][r]; }
}

// ---- gather node rows into level-sorted padded order, fp32 -> bf16 ----
__global__ __launch_bounds__(128) void k_gather(const float* __restrict__ X, const int* __restrict__ perm,
                                                const int* __restrict__ poff, const int* __restrict__ counts,
                                                unsigned short* __restrict__ Xg){
  int r = blockIdx.x, t = threadIdx.x;
  int total = poff[NL];
  int idx = -1;
  if(r<total){
    int lvl=0; while(r>=poff[lvl+1]) lvl++;
    if(r - poff[lvl] < counts[lvl]) idx = perm[r];
  }
  us4 pv = (us4){0,0,0,0};
  if(idx>=0){
    f32x4 x = *(const f32x4*)(X + (size_t)idx*D + t*4);
    #pragma unroll
    for(int e=0;e<4;e++) pv[e] = f2bf(x[e]);
  }
  *(us4*)(Xg + (size_t)r*D + t*4) = pv;
}

// ---- bf16 MFMA GEMM: Out[row][n] = Xs[row][:] @ WbT[n][:]  (Wt is pre-transposed) ----
// PROJ: per-level weights + bias + fp32 level-sum accumulation for means.
template<bool PROJ>
__global__ __launch_bounds__(256) void k_gemm(
    const unsigned short* __restrict__ Xs,
    const unsigned short* __restrict__ Wt,
    const float* __restrict__ bias,
    unsigned short* __restrict__ Out,
    float* __restrict__ sums,
    const int* __restrict__ poff,
    const int* __restrict__ counts)
{
  __shared__ unsigned short Asb[BM*64];   // 16KB, 16B-granule XOR swizzled
  __shared__ unsigned short Bsb[64*64];   // 8KB
  __shared__ float lsum[64];
  int row0 = blockIdx.x*BM;
  int total = poff[NL];
  if(row0 >= total) return;
  int n0 = blockIdx.y*64;
  int lvl = 0;
  if(PROJ){ while(row0 >= poff[lvl+1]) lvl++; }
  const unsigned short* Wb = PROJ ? (Wt + (size_t)lvl*D*D) : Wt;
  int tid = threadIdx.x;
  if(PROJ && tid<64) lsum[tid]=0.f;
  int l = tid&63, w=tid>>6;
  int wm = w>>1, wn = w&1;           // 2x2 waves -> 64x32 per wave
  int l15 = l&15, lhi = l>>4;
  f32x4 acc[4][2];
  #pragma unroll
  for(int i=0;i<4;i++)
    #pragma unroll
    for(int j=0;j<2;j++) acc[i][j] = (f32x4){0.f,0.f,0.f,0.f};

  for(int kt=0;kt<D/64;kt++){
    int k0 = kt*64;
    #pragma unroll
    for(int p=0;p<4;p++){             // stage A 128x64
      int flat = p*256+tid;
      int ar = flat>>3, ag = flat&7;
      short8 v = *(const short8*)(Xs + (size_t)(row0+ar)*D + k0 + ag*8);
      *(short8*)(Asb + ar*64 + ((ag^(ar&7))<<3)) = v;
    }
    #pragma unroll
    for(int p=0;p<2;p++){             // stage B^T 64x64
      int flat = p*256+tid;
      int br = flat>>3, bg = flat&7;
      short8 v = *(const short8*)(Wb + (size_t)(n0+br)*D + k0 + bg*8);
      *(short8*)(Bsb + br*64 + ((bg^(br&7))<<3)) = v;
    }
    __syncthreads();
    #pragma unroll
    for(int kk=0;kk<2;kk++){
      int swz = ((kk*4+lhi) ^ (l15&7))<<3;   // (row&7)==(l15&7) for all frag rows
      bf16x8 a[4], b[2];
      #pragma unroll
      for(int fm=0;fm<4;fm++)
        a[fm] = __builtin_bit_cast(bf16x8, *(const short8*)(Asb + (wm*64+fm*16+l15)*64 + swz));
      #pragma unroll
      for(int fn=0;fn<2;fn++)
        b[fn] = __builtin_bit_cast(bf16x8, *(const short8*)(Bsb + (wn*32+fn*16+l15)*64 + swz));
      #pragma unroll
      for(int fm=0;fm<4;fm++)
        #pragma unroll
        for(int fn=0;fn<2;fn++)
          acc[fm][fn] = __builtin_amdgcn_mfma_f32_16x16x32_bf16(a[fm], b[fn], acc[fm][fn], 0,0,0);
    }
    __syncthreads();
  }
  // epilogue: bias, bf16 store, masked column sums (for level means)
  int cnt=0, pb=0;
  if(PROJ){ cnt = counts[lvl]; pb = poff[lvl]; }
  float csum[2] = {0.f,0.f};
  #pragma unroll
  for(int fn=0;fn<2;fn++){
    int col = n0 + wn*32 + fn*16 + l15;
    float bia = PROJ ? bias[lvl*D + col] : 0.f;
    #pragma unroll
    for(int fm=0;fm<4;fm++){
      #pragma unroll
      for(int j=0;j<4;j++){
        int grow = row0 + wm*64 + fm*16 + lhi*4 + j;   // verified C/D mapping
        float v = acc[fm][fn][j] + bia;
        Out[(size_t)grow*D + col] = f2bf(v);
        if(PROJ && (grow-pb)<cnt) csum[fn] += v;
      }
    }
  }
  if(PROJ){
    #pragma unroll
    for(int fn=0;fn<2;fn++){
      float s = csum[fn];
      s += __shfl_xor(s,16);
      s += __shfl_xor(s,32);
      if(lhi==0) atomicAdd(&lsum[wn*32+fn*16+l15], s);
    }
    __syncthreads();
    if(tid<64) atomicAdd(&sums[(size_t)lvl*D + n0 + tid], lsum[tid]);
  }
}

// ---- means -> Bpre = means@W1b + b1 ; MW = means@Wout (both 8x512 fp32) ----
__global__ __launch_bounds__(128) void k_small(
    const float* __restrict__ sums, const int* __restrict__ counts,
    const float* __restrict__ W1b, const float* __restrict__ b1,
    const float* __restrict__ Wout, float* __restrict__ Bpre, float* __restrict__ MW)
{
  int lvl = blockIdx.x, jc = blockIdx.y, t = threadIdx.x;
  __shared__ float mean[D];
  int c = counts[lvl];
  float inv = 1.f / (float)(c>0?c:1);
  for(int k=t;k<D;k+=128) mean[k] = sums[lvl*D+k]*inv;
  __syncthreads();
  int j = jc*128 + t;
  float a=0.f, b=0.f;
  for(int k=0;k<D;k++){ float m = mean[k]; a += m*W1b[(size_t)k*D+j]; b += m*Wout[(size_t)k*D+j]; }
  Bpre[lvl*D+j] = a + b1[j];
  MW[lvl*D+j] = b;
}

// ---- fused: scores(tanh MLP) -> softmax -> o = wts@MW + bout -> LN -> ReLU -> scatter ----
__global__ __launch_bounds__(256) void k_score(
    const unsigned short* __restrict__ Ag, const int* __restrict__ perm,
    const int* __restrict__ poff, const int* __restrict__ counts,
    const float* __restrict__ Bpre, const float* __restrict__ MW,
    const float* __restrict__ w2, const float* __restrict__ b2,
    const float* __restrict__ bout, const float* __restrict__ gamma,
    const float* __restrict__ beta, float* __restrict__ out)
{
  int l = threadIdx.x & 63;
  int r = blockIdx.x*4 + (threadIdx.x>>6);   // one wave per row
  int total = poff[NL];
  if(r >= total) return;
  int lvl=0; while(r>=poff[lvl+1]) lvl++;
  if(r - poff[lvl] >= counts[lvl]) return;   // padding row
  int orig = perm[r];
  short8 av = *(const short8*)(Ag + (size_t)r*D + l*8);
  float a[8], w2v[8];
  #pragma unroll
  for(int e=0;e<8;e++){ a[e] = bf2f((unsigned short)av[e]); w2v[e] = w2[l*8+e]; }
  float sc[NL];
  #pragma unroll
  for(int lev=0;lev<NL;lev++){
    float s = 0.f;
    #pragma unroll
    for(int e=0;e<8;e++) s += w2v[e]*tanh_fast(a[e] + Bpre[lev*D + l*8 + e]);
    #pragma unroll
    for(int off=1; off<64; off<<=1) s += __shfl_xor(s, off);
    sc[lev] = s;
  }
  float b2v = b2[0];
  float mx = -1e30f;
  #pragma unroll
  for(int lev=0;lev<NL;lev++){ sc[lev]+=b2v; if(counts[lev]>0) mx = fmaxf(mx, sc[lev]); }
  float den=0.f, wts[NL];
  #pragma unroll
  for(int lev=0;lev<NL;lev++){ float e = (counts[lev]>0) ? __expf(sc[lev]-mx) : 0.f; wts[lev]=e; den+=e; }
  float iden = 1.f/den;
  #pragma unroll
  for(int lev=0;lev<NL;lev++) wts[lev]*=iden;
  float o[8]; float s1=0.f;
  #pragma unroll
  for(int q=0;q<8;q++){
    int c = l + 64*q;
    float v = bout[c];
    #pragma unroll
    for(int lev=0;lev<NL;lev++) v += wts[lev]*MW[lev*D + c];
    o[q]=v; s1+=v;
  }
  #pragma unroll
  for(int off=1; off<64; off<<=1) s1 += __shfl_xor(s1,off);
  float mu = s1 * (1.f/512.f);
  float s2=0.f;
  #pragma unroll
  for(int q=0;q<8;q++){ float d=o[q]-mu; s2 += d*d; }
  #pragma unroll
  for(int off=1; off<64; off<<=1) s2 += __shfl_xor(s2,off);
  float rs = rsqrtf(s2*(1.f/512.f) + 1e-5f);
  #pragma unroll
  for(int q=0;q<8;q++){
    int c = l + 64*q;
    float y = (o[q]-mu)*rs*gamma[c] + beta[c];
    out[(size_t)orig*D + c] = fmaxf(y, 0.f);
  }
}

extern "C" void kernel_launch(void* const* d_in, const int* in_sizes, int n_in,
                              void* d_out, int out_size, void* d_ws, size_t ws_size,
                              hipStream_t stream) {
  (void)in_sizes; (void)n_in; (void)out_size; (void)ws_size;
  const float* X    = (const float*)d_in[0];
  const int*   lv   = (const int*)  d_in[1];
  const float* Wp   = (const float*)d_in[2];
  const float* bp   = (const float*)d_in[3];
  const float* W1a  = (const float*)d_in[4];
  const float* W1b  = (const float*)d_in[5];
  const float* b1   = (const float*)d_in[6];
  const float* w2   = (const float*)d_in[7];
  const float* b2   = (const float*)d_in[8];
  const float* Wout = (const float*)d_in[9];
  const float* bout = (const float*)d_in[10];
  const float* gmma = (const float*)d_in[11];
  const float* beta = (const float*)d_in[12];
  float* out = (float*)d_out;

  char* ws = (char*)d_ws;
  int*   counts  = (int*)(ws+0);        // 8
  int*   cursors = (int*)(ws+64);       // 8
  int*   poff    = (int*)(ws+128);      // 9
  float* sums    = (float*)(ws+256);    // 8*512
  float* Bpre    = (float*)(ws+16640);  // 8*512
  float* MW      = (float*)(ws+33024);  // 8*512
  int*   perm    = (int*)(ws+49664);    // 33792
  unsigned short* WtP  = (unsigned short*)(ws+186368);          // 8*512*512 bf16
  unsigned short* Wt1a = WtP + (size_t)NL*D*D;                  // 512*512 bf16
  unsigned short* Xg   = (unsigned short*)(ws+4905472);         // 33792*512 bf16
  unsigned short* Hg   = (unsigned short*)(ws+39508480);        // 33792*512 bf16
  unsigned short* Ag   = Xg;   // Xg dead after proj GEMM

  k_zero   <<<dim3(9),   dim3(512), 0, stream>>>((float*)ws);
  k_hist   <<<dim3(64),  dim3(256), 0, stream>>>(lv, counts);
  k_offsets<<<dim3(1),   dim3(64),  0, stream>>>(counts, poff, cursors);
  k_scatter<<<dim3(128), dim3(256), 0, stream>>>(lv, cursors, perm);
  k_trans  <<<dim3(8,8,9), dim3(256), 0, stream>>>(Wp, W1a, WtP, Wt1a);
  k_gather <<<dim3(PADMAX), dim3(128), 0, stream>>>(X, perm, poff, counts, Xg);
  k_gemm<true> <<<dim3(MT_MAX,8), dim3(256), 0, stream>>>(Xg, WtP, bp, Hg, sums, poff, counts);
  k_small  <<<dim3(8,4), dim3(128), 0, stream>>>(sums, counts, W1b, b1, Wout, Bpre, MW);
  k_gemm<false><<<dim3(MT_MAX,8), dim3(256), 0, stream>>>(Hg, Wt1a, nullptr, Ag, sums, poff, counts);
  k_score  <<<dim3(PADMAX/4), dim3(256), 0, stream>>>(Ag, perm, poff, counts, Bpre, MW,
                                                      w2, b2, bout, gmma, beta, out);
}